// Round 6
// baseline (49.710 us; speedup 1.0000x reference)
//
#include <hip/hip_runtime.h>

// SASA local self-attention, fully fused, f32 I/O.
// B=4, C=64, H=W=96, g=8, og=ig=8, k=7, pad=3.
// Block = (b, group, channel-quarter) x 32x32 tile; 2 output channels/block.
// 256 threads; each owns a 2x2 pixel quad (rows/cols share 7/8 of the window)
// -> per-output LDS reads cut 1.75x vs 2x1 blocking.
// k,v interleaved float2 in LDS (row stride 39, odd -> spread banks).
// exp2-prescaled softmax, no max-subtraction (|logit|*log2e << 127).
// XCD-aware bijective block swizzle (1152 % 8 == 0).

constexpr int Bc = 4, Cc = 64, Hc = 96, Wc = 96;
constexpr int G = 8, OG = 8, IG = 8, KK = 7, PAD = 3;
constexpr int TH = 32, TW = 32;
constexpr int SH = TH + KK - 1;    // 38 halo rows
constexpr int SWD = TW + KK - 1;   // 38 halo cols (data)
constexpr int SW2 = 39;            // LDS row stride in float2 units (odd)
constexpr int TILES_H = Hc / TH, TILES_W = Wc / TW;  // 3 x 3
constexpr int TILES = TILES_H * TILES_W;             // 9
constexpr int PLANE = Hc * Wc;
constexpr int OCB = 2;             // output channels per block (4 quarters)
constexpr int NB = Bc * G * 4 * TILES;               // 1152
constexpr float LOG2E = 1.4426950408889634f;

// Attention over the 2x2 pixel quad. HALFC literal: 0 -> emb varies with patch
// row i; 1 -> varies with patch col j.
#define OC_LOOP(HALFC)                                                             \
  _Pragma("unroll 1")                                                              \
  for (int oc = 0; oc < OCB; ++oc) {                                               \
    const float qv00 = qvs[oc][0], qv01 = qvs[oc][1];                              \
    const float qv10 = qvs[oc][2], qv11 = qvs[oc][3];                              \
    float qe00[KK], qe01[KK], qe10[KK], qe11[KK];                                  \
    _Pragma("unroll")                                                              \
    for (int t = 0; t < KK; ++t) {                                                 \
      const float e = eb[oc * KK + t];                                             \
      qe00[t] = qv00 * e; qe01[t] = qv01 * e;                                      \
      qe10[t] = qv10 * e; qe11[t] = qv11 * e;                                      \
    }                                                                              \
    float s00a=0.f,s00b=0.f,o00a=0.f,o00b=0.f;                                     \
    float s01a=0.f,s01b=0.f,o01a=0.f,o01b=0.f;                                     \
    float s10a=0.f,s10b=0.f,o10a=0.f,o10b=0.f;                                     \
    float s11a=0.f,s11b=0.f,o11a=0.f,o11b=0.f;                                     \
    const float2* rp = &kvs[oc][r0][c0];                                           \
    _Pragma("unroll")                                                              \
    for (int i = 0; i < 8; ++i) {                                                  \
      float2 row[8];                                                               \
      _Pragma("unroll")                                                            \
      for (int jj = 0; jj < 8; ++jj) row[jj] = rp[i * SW2 + jj];                   \
      if (i < 7) {                                                                 \
        _Pragma("unroll")                                                          \
        for (int j = 0; j < KK; ++j) {                                             \
          const float e0 = __builtin_amdgcn_exp2f(                                 \
              fmaf(qv00, row[j].x,     (HALFC) ? qe00[j] : qe00[i]));              \
          const float e1 = __builtin_amdgcn_exp2f(                                 \
              fmaf(qv01, row[j + 1].x, (HALFC) ? qe01[j] : qe01[i]));              \
          if (j & 1) { s00b += e0; o00b = fmaf(e0, row[j].y,     o00b);            \
                       s01b += e1; o01b = fmaf(e1, row[j + 1].y, o01b); }          \
          else       { s00a += e0; o00a = fmaf(e0, row[j].y,     o00a);            \
                       s01a += e1; o01a = fmaf(e1, row[j + 1].y, o01a); }          \
        }                                                                          \
      }                                                                            \
      if (i >= 1) {                                                                \
        _Pragma("unroll")                                                          \
        for (int j = 0; j < KK; ++j) {                                             \
          const float e0 = __builtin_amdgcn_exp2f(                                 \
              fmaf(qv10, row[j].x,     (HALFC) ? qe10[j] : qe10[i - 1]));          \
          const float e1 = __builtin_amdgcn_exp2f(                                 \
              fmaf(qv11, row[j + 1].x, (HALFC) ? qe11[j] : qe11[i - 1]));          \
          if (j & 1) { s10b += e0; o10b = fmaf(e0, row[j].y,     o10b);            \
                       s11b += e1; o11b = fmaf(e1, row[j + 1].y, o11b); }          \
          else       { s10a += e0; o10a = fmaf(e0, row[j].y,     o10a);            \
                       s11a += e1; o11a = fmaf(e1, row[j + 1].y, o11a); }          \
        }                                                                          \
      }                                                                            \
    }                                                                              \
    float2 r0v, r1v;                                                               \
    r0v.x = (o00a + o00b) * __builtin_amdgcn_rcpf(s00a + s00b);                    \
    r0v.y = (o01a + o01b) * __builtin_amdgcn_rcpf(s01a + s01b);                    \
    r1v.x = (o10a + o10b) * __builtin_amdgcn_rcpf(s10a + s10b);                    \
    r1v.y = (o11a + o11b) * __builtin_amdgcn_rcpf(s11a + s11b);                    \
    *(float2*)(ob + oc * PLANE)      = r0v;                                        \
    *(float2*)(ob + oc * PLANE + Wc) = r1v;                                        \
  }

__global__ __launch_bounds__(256, 4)
void sasa_kernel(const float* __restrict__ x,
                 const float* __restrict__ wq,
                 const float* __restrict__ wk,
                 const float* __restrict__ wv,
                 const float* __restrict__ h_emb,
                 const float* __restrict__ w_emb,
                 float* __restrict__ out)
{
    __shared__ float2 kvs[OCB][SH][SW2];   // 23712 B

    const int tid = threadIdx.x;
    // XCD-aware bijective swizzle: each XCD owns 144 consecutive logical blocks.
    const int L = (blockIdx.x & 7) * (NB / 8) + (blockIdx.x >> 3);
    const int tile    = L % TILES;
    const int rest    = L / TILES;
    const int quarter = rest & 3;          // oc_global = quarter*2 + {0,1}
    const int gi      = (rest >> 2) & 7;
    const int b       = rest >> 5;
    const int half    = quarter >> 1;      // 0 -> h_emb, 1 -> w_emb
    const int th0     = (tile / TILES_W) * TH;
    const int tw0     = (tile % TILES_W) * TW;

    const float* xb  = x  + (size_t)(b * Cc + gi * IG) * PLANE;
    const float* wqg = wq + gi * OG * IG + quarter * OCB * IG;  // block-uniform
    const float* wkg = wk + gi * OG * IG + quarter * OCB * IG;
    const float* wvg = wv + gi * OG * IG + quarter * OCB * IG;
    const float* eb  = (half ? w_emb : h_emb) + gi * (OG / 2) * KK
                                              + (quarter & 1) * OCB * KK;

    // ---- q-pixel loads issued first so HBM latency hides under phase 1 ----
    const int tx = tid & 15;
    const int r0 = 2 * (tid >> 4);   // local rows r0, r0+1
    const int c0 = 2 * tx;           // local cols c0, c0+1
    const int h0 = th0 + r0;
    const int w0 = tw0 + c0;
    float2 xr0[IG], xr1[IG];         // (c0, c0+1) for rows h0, h0+1
    {
        const float* xp = xb + (size_t)h0 * Wc + w0;
        #pragma unroll
        for (int i = 0; i < IG; ++i) {
            xr0[i] = *(const float2*)(xp + i * PLANE);
            xr1[i] = *(const float2*)(xp + i * PLANE + Wc);
        }
    }

    // ---- Phase 1: k,v (grouped 1x1 conv) over 38x38 halo -> LDS float2 ----
    for (int e = tid; e < SH * SWD; e += 256) {
        const int hy = e / SWD, hx = e - hy * SWD;
        const int gy = th0 + hy - PAD;
        const int gx = tw0 + hx - PAD;
        const bool valid = ((unsigned)gy < (unsigned)Hc) && ((unsigned)gx < (unsigned)Wc);
        float xv[IG];
        #pragma unroll
        for (int i = 0; i < IG; ++i)
            xv[i] = valid ? xb[i * PLANE + gy * Wc + gx] : 0.0f;
        #pragma unroll
        for (int oc = 0; oc < OCB; ++oc) {
            float ka = 0.f, va = 0.f;
            #pragma unroll
            for (int i = 0; i < IG; ++i) {
                ka = fmaf(xv[i], wkg[oc * IG + i], ka);
                va = fmaf(xv[i], wvg[oc * IG + i], va);
            }
            kvs[oc][hy][hx] = make_float2(ka, va);
        }
    }

    // q projections for the 2x2 quad before the barrier; xr registers retire.
    float qvs[OCB][4];
    #pragma unroll
    for (int oc = 0; oc < OCB; ++oc) {
        float q00 = 0.f, q01 = 0.f, q10 = 0.f, q11 = 0.f;
        #pragma unroll
        for (int i = 0; i < IG; ++i) {
            const float wqi = wqg[oc * IG + i];
            q00 = fmaf(xr0[i].x, wqi, q00);
            q01 = fmaf(xr0[i].y, wqi, q01);
            q10 = fmaf(xr1[i].x, wqi, q10);
            q11 = fmaf(xr1[i].y, wqi, q11);
        }
        qvs[oc][0] = q00 * LOG2E;
        qvs[oc][1] = q01 * LOG2E;
        qvs[oc][2] = q10 * LOG2E;
        qvs[oc][3] = q11 * LOG2E;
    }
    __syncthreads();

    // ---- Phase 2: attention over the 2x2 quad ----
    float* ob = out + (size_t)(b * Cc + gi * OG + quarter * OCB) * PLANE
                    + (size_t)h0 * Wc + w0;

    if (half == 0) { OC_LOOP(0) } else { OC_LOOP(1) }
}

extern "C" void kernel_launch(void* const* d_in, const int* in_sizes, int n_in,
                              void* d_out, int out_size, void* d_ws, size_t ws_size,
                              hipStream_t stream)
{
    const float* x     = (const float*)d_in[0];
    const float* wq    = (const float*)d_in[1];
    const float* wk    = (const float*)d_in[2];
    const float* wv    = (const float*)d_in[3];
    const float* h_emb = (const float*)d_in[4];
    const float* w_emb = (const float*)d_in[5];
    float* out = (float*)d_out;

    sasa_kernel<<<NB, 256, 0, stream>>>(x, wq, wk, wv, h_emb, w_emb, out);
}

// Round 7
// 40.191 us; speedup vs baseline: 1.2368x; 1.2368x over previous
//
#include <hip/hip_runtime.h>

// SASA local self-attention, split producer/consumer, f32 I/O.
// B=4, C=64, H=W=96, g=8, og=ig=8, k=7, pad=3.
//
// Kernel A (qkv): grouped 1x1 conv once for ALL channels.
//   q  -> d_ws [B][C][96][96] f32 (channel-planar, matches out layout)
//   k,v-> d_ws [B][G][8][102][104] float2 (zero-padded borders baked in)
// Kernel B (attn): R5-proven structure — 32x16 tile, 2 oc/block, 2 rows/thread,
//   k/v staged LDS via plain float2 copies, exp2 softmax without max-sub.
// ws usage: 21,725,184 B (kv) + 9,437,184 B (q) = 31,162,368 B.

constexpr int Bc = 4, Cc = 64, Hc = 96, Wc = 96;
constexpr int G = 8, OG = 8, IG = 8, KK = 7, PAD = 3;
constexpr int HP = 102, WPS = 104;                   // padded rows, row stride
constexpr int KVPLANE = HP * WPS;                    // float2 per (b,g,oc) plane
constexpr int TH = 32, TW = 16;
constexpr int SH = TH + KK - 1;                      // 38 halo rows
constexpr int SWD = TW + KK - 1;                     // 22 halo cols
constexpr int SW2 = 25;                              // LDS row stride (float2)
constexpr int TILES_H = Hc / TH, TILES_W = Wc / TW;  // 3 x 6
constexpr int TILES = TILES_H * TILES_W;             // 18
constexpr int PLANE = Hc * Wc;
constexpr int OCB = 2;
constexpr int NB = Bc * G * 4 * TILES;               // 2304
constexpr float LOG2E = 1.4426950408889634f;

// ---------------- Kernel A: q,k,v producer ----------------
__global__ __launch_bounds__(256)
void qkv_kernel(const float* __restrict__ x,
                const float* __restrict__ wq,
                const float* __restrict__ wk,
                const float* __restrict__ wv,
                float2* __restrict__ kv,
                float* __restrict__ q)
{
    const int bg = blockIdx.y;                 // b*8 + gi, block-uniform
    const int gi = bg & 7, b = bg >> 3;
    const int p  = blockIdx.x * 256 + threadIdx.x;
    if (p >= HP * HP) return;                  // 10404 padded data points
    const int hp = p / HP, wp = p % HP;
    const int gy = hp - PAD, gx = wp - PAD;
    const bool valid = ((unsigned)gy < (unsigned)Hc) && ((unsigned)gx < (unsigned)Wc);

    const float* xb  = x  + (size_t)(b * Cc + gi * IG) * PLANE;
    const float* wqg = wq + gi * OG * IG;      // block-uniform -> scalar loads
    const float* wkg = wk + gi * OG * IG;
    const float* wvg = wv + gi * OG * IG;

    float xv[IG];
    #pragma unroll
    for (int i = 0; i < IG; ++i)
        xv[i] = valid ? xb[i * PLANE + gy * Wc + gx] : 0.0f;

    float2* kvb = kv + (size_t)(bg * OG) * KVPLANE + hp * WPS + wp;
    float*  qb  = q  + (size_t)(b * Cc + gi * OG) * PLANE + gy * Wc + gx;

    #pragma unroll
    for (int oc = 0; oc < OG; ++oc) {
        float ka = 0.f, va = 0.f, qa = 0.f;
        #pragma unroll
        for (int i = 0; i < IG; ++i) {
            ka = fmaf(xv[i], wkg[oc * IG + i], ka);
            va = fmaf(xv[i], wvg[oc * IG + i], va);
            qa = fmaf(xv[i], wqg[oc * IG + i], qa);
        }
        kvb[(size_t)oc * KVPLANE] = make_float2(ka, va);
        if (valid) qb[(size_t)oc * PLANE] = qa;
    }
}

// ---------------- Kernel B: attention consumer ----------------
// Attention tap loops. HALFC literal 0 (emb varies with row i) / 1 (with col j).
#define OC_LOOP(HALFC)                                                            \
  _Pragma("unroll 1")                                                             \
  for (int oc = 0; oc < OCB; ++oc) {                                              \
    const float qv0 = qvs[oc][0], qv1 = qvs[oc][1];                               \
    float qe0[KK], qe1[KK];                                                       \
    _Pragma("unroll")                                                             \
    for (int t = 0; t < KK; ++t) {                                                \
      const float e = eb[oc * KK + t];                                            \
      qe0[t] = qv0 * e; qe1[t] = qv1 * e;                                         \
    }                                                                             \
    float s0a = 0.f, s0b = 0.f, o0a = 0.f, o0b = 0.f;                             \
    float s1a = 0.f, s1b = 0.f, o1a = 0.f, o1b = 0.f;                             \
    const float2* rp = &kvs[oc][r0][tx];                                          \
    _Pragma("unroll")                                                             \
    for (int i = 0; i < 8; ++i) {                                                 \
      float2 row[KK];                                                             \
      _Pragma("unroll")                                                           \
      for (int j = 0; j < KK; ++j) row[j] = rp[i * SW2 + j];                      \
      if (i < 7) {                                                                \
        _Pragma("unroll")                                                         \
        for (int j = 0; j < KK; ++j) {                                            \
          const float ev = __builtin_amdgcn_exp2f(                                \
              fmaf(qv0, row[j].x, (HALFC) ? qe0[j] : qe0[i]));                    \
          if (j & 1) { s0b += ev; o0b = fmaf(ev, row[j].y, o0b); }                \
          else       { s0a += ev; o0a = fmaf(ev, row[j].y, o0a); }                \
        }                                                                         \
      }                                                                           \
      if (i >= 1) {                                                               \
        _Pragma("unroll")                                                         \
        for (int j = 0; j < KK; ++j) {                                            \
          const float ev = __builtin_amdgcn_exp2f(                                \
              fmaf(qv1, row[j].x, (HALFC) ? qe1[j] : qe1[i - 1]));                \
          if (j & 1) { s1b += ev; o1b = fmaf(ev, row[j].y, o1b); }                \
          else       { s1a += ev; o1a = fmaf(ev, row[j].y, o1a); }                \
        }                                                                         \
      }                                                                           \
    }                                                                             \
    ob[oc * PLANE]      = (o0a + o0b) * __builtin_amdgcn_rcpf(s0a + s0b);         \
    ob[oc * PLANE + Wc] = (o1a + o1b) * __builtin_amdgcn_rcpf(s1a + s1b);         \
  }

__global__ __launch_bounds__(256, 8)
void attn_kernel(const float2* __restrict__ kv,
                 const float* __restrict__ q,
                 const float* __restrict__ h_emb,
                 const float* __restrict__ w_emb,
                 float* __restrict__ out)
{
    __shared__ float2 kvs[OCB][SH][SW2];   // 15200 B

    const int tid = threadIdx.x;
    // XCD-aware bijective swizzle: each XCD owns 288 consecutive logical blocks.
    const int L = (blockIdx.x & 7) * (NB / 8) + (blockIdx.x >> 3);
    const int tile    = L % TILES;
    const int rest    = L / TILES;
    const int quarter = rest & 3;          // oc_global = quarter*2 + {0,1}
    const int gi      = (rest >> 2) & 7;
    const int b       = rest >> 5;
    const int half    = quarter >> 1;      // 0 -> h_emb, 1 -> w_emb
    const int th0     = (tile / TILES_W) * TH;
    const int tw0     = (tile % TILES_W) * TW;

    const float* eb = (half ? w_emb : h_emb) + gi * (OG / 2) * KK
                                             + (quarter & 1) * OCB * KK;

    const int tx = tid & 15;
    const int r0 = 2 * (tid >> 4);
    const int h0 = th0 + r0;
    const int wg = tw0 + tx;

    // q loads first (tiny; latency hides under staging)
    float qvs[OCB][2];
    {
        const float* qp = q + (size_t)(b * Cc + gi * OG + quarter * OCB) * PLANE
                            + (size_t)h0 * Wc + wg;
        #pragma unroll
        for (int oc = 0; oc < OCB; ++oc) {
            qvs[oc][0] = qp[oc * PLANE] * LOG2E;
            qvs[oc][1] = qp[oc * PLANE + Wc] * LOG2E;
        }
    }

    // ---- Phase 1: stage k,v halo (38x22) for both oc via plain copies ----
    const float2* kvg = kv + (size_t)((b * G + gi) * OG + quarter * OCB) * KVPLANE;
    for (int e = tid; e < 2 * SH * SWD; e += 256) {
        const int oc = e / (SH * SWD);
        const int r  = e - oc * (SH * SWD);
        const int hy = r / SWD, hx = r - hy * SWD;
        kvs[oc][hy][hx] = kvg[(size_t)oc * KVPLANE + (th0 + hy) * WPS + (tw0 + hx)];
    }
    __syncthreads();

    // ---- Phase 2: attention; thread owns pixels (r0, tx) and (r0+1, tx) ----
    float* ob = out + (size_t)(b * Cc + gi * OG + quarter * OCB) * PLANE
                    + (size_t)h0 * Wc + wg;

    if (half == 0) { OC_LOOP(0) } else { OC_LOOP(1) }
}

extern "C" void kernel_launch(void* const* d_in, const int* in_sizes, int n_in,
                              void* d_out, int out_size, void* d_ws, size_t ws_size,
                              hipStream_t stream)
{
    const float* x     = (const float*)d_in[0];
    const float* wq    = (const float*)d_in[1];
    const float* wk    = (const float*)d_in[2];
    const float* wv    = (const float*)d_in[3];
    const float* h_emb = (const float*)d_in[4];
    const float* w_emb = (const float*)d_in[5];
    float* out = (float*)d_out;

    float2* kv = (float2*)d_ws;                                   // 21,725,184 B
    float*  qb = (float*)((char*)d_ws + (size_t)Bc * G * OG * KVPLANE * sizeof(float2));

    dim3 gridA((HP * HP + 255) / 256, Bc * G);                    // 41 x 32
    qkv_kernel<<<gridA, 256, 0, stream>>>(x, wq, wk, wv, kv, qb);
    attn_kernel<<<NB, 256, 0, stream>>>(kv, qb, h_emb, w_emb, out);
}

// Round 8
// 36.159 us; speedup vs baseline: 1.3748x; 1.1115x over previous
//
#include <hip/hip_runtime.h>

// SASA local self-attention, fully fused, f32 I/O.
// B=4, C=64, H=W=96, g=8, og=ig=8, k=7, pad=3.
// Block = (b, group, channel-quarter) x 32x16 tile; 2 output channels/block.
// 256 threads, each owns 2 vertically-adjacent pixels.
// k,v for BOTH channels interleaved as float4 (k0,v0,k1,v1) in LDS
// -> ONE ds_read_b128 per tap serves 2 channels (56 LDS insts/thread).
// Row stride 23 float4 -> 16B aligned, 2-row thread groups spread over banks.
// exp2-prescaled softmax, no max-subtraction (|logit|*log2e << 127).
// XCD-aware bijective block swizzle (2304 % 8 == 0).

constexpr int Bc = 4, Cc = 64, Hc = 96, Wc = 96;
constexpr int G = 8, OG = 8, IG = 8, KK = 7, PAD = 3;
constexpr int TH = 32, TW = 16;
constexpr int SH = TH + KK - 1;    // 38 halo rows
constexpr int SWD = TW + KK - 1;   // 22 halo cols (data)
constexpr int SW4 = 23;            // LDS row stride in float4 units
constexpr int TILES_H = Hc / TH, TILES_W = Wc / TW;  // 3 x 6
constexpr int TILES = TILES_H * TILES_W;             // 18
constexpr int PLANE = Hc * Wc;
constexpr int OCB = 2;             // output channels per block (4 quarters)
constexpr int NB = Bc * G * 4 * TILES;               // 2304
constexpr float LOG2E = 1.4426950408889634f;

// Phase-2 tap loops. HALFC literal: 0 -> emb varies with patch row, 1 -> col.
// 4 independent streams: (oc0,px0) (oc1,px0) (oc0,px1) (oc1,px1).
#define PHASE2(HALFC)                                                             \
  {                                                                               \
    float sa[2][2] = {{0.f,0.f},{0.f,0.f}}, sb[2][2] = {{0.f,0.f},{0.f,0.f}};     \
    float oa[2][2] = {{0.f,0.f},{0.f,0.f}}, obv[2][2] = {{0.f,0.f},{0.f,0.f}};    \
    const float4* rp = &kvs[r0][tx];                                              \
    _Pragma("unroll")                                                             \
    for (int i = 0; i < 8; ++i) {                                                 \
      float4 row[8];                                                              \
      _Pragma("unroll")                                                           \
      for (int jj = 0; jj < 8; ++jj) row[jj] = rp[i * SW4 + jj];                  \
      if (i < 7) {                                                                \
        _Pragma("unroll")                                                         \
        for (int j = 0; j < KK; ++j) {                                            \
          const float ev0 = __builtin_amdgcn_exp2f(                               \
              fmaf(qv[0][0], row[j].x, qe[0][0][(HALFC) ? j : i]));               \
          const float ev1 = __builtin_amdgcn_exp2f(                               \
              fmaf(qv[1][0], row[j].z, qe[1][0][(HALFC) ? j : i]));               \
          if (j & 1) { sb[0][0] += ev0; obv[0][0] = fmaf(ev0, row[j].y, obv[0][0]);\
                       sb[1][0] += ev1; obv[1][0] = fmaf(ev1, row[j].w, obv[1][0]);}\
          else       { sa[0][0] += ev0; oa[0][0] = fmaf(ev0, row[j].y, oa[0][0]); \
                       sa[1][0] += ev1; oa[1][0] = fmaf(ev1, row[j].w, oa[1][0]);}\
        }                                                                         \
      }                                                                           \
      if (i >= 1) {                                                               \
        _Pragma("unroll")                                                         \
        for (int j = 0; j < KK; ++j) {                                            \
          const float ev0 = __builtin_amdgcn_exp2f(                               \
              fmaf(qv[0][1], row[j].x, qe[0][1][(HALFC) ? j : (i - 1)]));         \
          const float ev1 = __builtin_amdgcn_exp2f(                               \
              fmaf(qv[1][1], row[j].z, qe[1][1][(HALFC) ? j : (i - 1)]));         \
          if (j & 1) { sb[0][1] += ev0; obv[0][1] = fmaf(ev0, row[j].y, obv[0][1]);\
                       sb[1][1] += ev1; obv[1][1] = fmaf(ev1, row[j].w, obv[1][1]);}\
          else       { sa[0][1] += ev0; oa[0][1] = fmaf(ev0, row[j].y, oa[0][1]); \
                       sa[1][1] += ev1; oa[1][1] = fmaf(ev1, row[j].w, oa[1][1]);}\
        }                                                                         \
      }                                                                           \
    }                                                                             \
    _Pragma("unroll")                                                             \
    for (int oc = 0; oc < OCB; ++oc) {                                            \
      ob[oc * PLANE]      = (oa[oc][0] + obv[oc][0])                              \
                            * __builtin_amdgcn_rcpf(sa[oc][0] + sb[oc][0]);       \
      ob[oc * PLANE + Wc] = (oa[oc][1] + obv[oc][1])                              \
                            * __builtin_amdgcn_rcpf(sa[oc][1] + sb[oc][1]);       \
    }                                                                             \
  }

__global__ __launch_bounds__(256)
void sasa_kernel(const float* __restrict__ x,
                 const float* __restrict__ wq,
                 const float* __restrict__ wk,
                 const float* __restrict__ wv,
                 const float* __restrict__ h_emb,
                 const float* __restrict__ w_emb,
                 float* __restrict__ out)
{
    __shared__ float4 kvs[SH][SW4];    // 13,984 B

    const int tid = threadIdx.x;
    // XCD-aware bijective swizzle: each XCD owns 288 consecutive logical blocks.
    const int L = (blockIdx.x & 7) * (NB / 8) + (blockIdx.x >> 3);
    const int tile    = L % TILES;
    const int rest    = L / TILES;
    const int quarter = rest & 3;      // oc_global = quarter*2 + {0,1}
    const int gi      = (rest >> 2) & 7;
    const int b       = rest >> 5;
    const int half    = quarter >> 1;  // 0 -> h_emb, 1 -> w_emb
    const int th0     = (tile / TILES_W) * TH;
    const int tw0     = (tile % TILES_W) * TW;

    const float* xb  = x  + (size_t)(b * Cc + gi * IG) * PLANE;
    const float* wqg = wq + gi * OG * IG + quarter * OCB * IG;  // block-uniform
    const float* wkg = wk + gi * OG * IG + quarter * OCB * IG;
    const float* wvg = wv + gi * OG * IG + quarter * OCB * IG;
    const float* eb  = (half ? w_emb : h_emb) + gi * (OG / 2) * KK
                                              + (quarter & 1) * OCB * KK;

    // ---- q-pixel loads issued first so HBM latency hides under phase 1 ----
    const int tx = tid & 15;
    const int r0 = 2 * (tid >> 4);     // local rows r0, r0+1
    const int h0 = th0 + r0;
    const int wg = tw0 + tx;
    float xc0[IG], xc1[IG];
    {
        const float* xp = xb + (size_t)h0 * Wc + wg;
        #pragma unroll
        for (int i = 0; i < IG; ++i) {
            xc0[i] = xp[i * PLANE];
            xc1[i] = xp[i * PLANE + Wc];
        }
    }

    // ---- Phase 1: k,v (grouped 1x1 conv) over 38x22 halo -> LDS float4 ----
    for (int e = tid; e < SH * SWD; e += 256) {
        const int hy = e / SWD, hx = e - hy * SWD;
        const int gy = th0 + hy - PAD;
        const int gx = tw0 + hx - PAD;
        const bool valid = ((unsigned)gy < (unsigned)Hc) && ((unsigned)gx < (unsigned)Wc);
        float xv[IG];
        #pragma unroll
        for (int i = 0; i < IG; ++i)
            xv[i] = valid ? xb[i * PLANE + gy * Wc + gx] : 0.0f;
        float k0 = 0.f, v0 = 0.f, k1 = 0.f, v1 = 0.f;
        #pragma unroll
        for (int i = 0; i < IG; ++i) {
            k0 = fmaf(xv[i], wkg[i],      k0);
            v0 = fmaf(xv[i], wvg[i],      v0);
            k1 = fmaf(xv[i], wkg[IG + i], k1);
            v1 = fmaf(xv[i], wvg[IG + i], v1);
        }
        kvs[hy][hx] = make_float4(k0, v0, k1, v1);
    }

    // q projections + qe precompute before the barrier; xc registers retire.
    float qv[2][2];                    // [oc][px]
    #pragma unroll
    for (int oc = 0; oc < OCB; ++oc) {
        float q0 = 0.f, q1 = 0.f;
        #pragma unroll
        for (int i = 0; i < IG; ++i) {
            const float wqi = wqg[oc * IG + i];
            q0 = fmaf(xc0[i], wqi, q0);
            q1 = fmaf(xc1[i], wqi, q1);
        }
        qv[oc][0] = q0 * LOG2E;
        qv[oc][1] = q1 * LOG2E;
    }
    float qe[2][2][KK];                // [oc][px][t]
    #pragma unroll
    for (int oc = 0; oc < OCB; ++oc)
        #pragma unroll
        for (int t = 0; t < KK; ++t) {
            const float e = eb[oc * KK + t];
            qe[oc][0][t] = qv[oc][0] * e;
            qe[oc][1][t] = qv[oc][1] * e;
        }
    __syncthreads();

    // ---- Phase 2: attention; thread owns pixels (r0, tx) and (r0+1, tx) ----
    float* ob = out + (size_t)(b * Cc + gi * OG + quarter * OCB) * PLANE
                    + (size_t)h0 * Wc + wg;

    if (half == 0) { PHASE2(0) } else { PHASE2(1) }
}

extern "C" void kernel_launch(void* const* d_in, const int* in_sizes, int n_in,
                              void* d_out, int out_size, void* d_ws, size_t ws_size,
                              hipStream_t stream)
{
    const float* x     = (const float*)d_in[0];
    const float* wq    = (const float*)d_in[1];
    const float* wk    = (const float*)d_in[2];
    const float* wv    = (const float*)d_in[3];
    const float* h_emb = (const float*)d_in[4];
    const float* w_emb = (const float*)d_in[5];
    float* out = (float*)d_out;

    sasa_kernel<<<NB, 256, 0, stream>>>(x, wq, wk, wv, h_emb, w_emb, out);
}

// Round 9
// 33.374 us; speedup vs baseline: 1.4895x; 1.0835x over previous
//
#include <hip/hip_runtime.h>

// SASA local self-attention, fully fused, f32 I/O.
// B=4, C=64, H=W=96, g=8, og=ig=8, k=7, pad=3.
// Block = (b, group, channel-quarter) x 32x16 tile; 2 output channels/block.
// 128 threads, each owns FOUR vertically-adjacent pixels (share 10 halo rows)
// -> 140 ds_read_b64 per thread for 8 outputs (140 B/output, was 224).
// k,v float2 in LDS, row stride 25 (wave groups r0={0,4,8,12} -> word phases
// {0,8,16,24} -> all 16 bank-pairs covered evenly = structural-minimum 4 cyc).
// exp2-prescaled softmax, no max-subtraction (|logit|*log2e << 127).
// XCD-aware bijective block swizzle (2304 % 8 == 0).

constexpr int Bc = 4, Cc = 64, Hc = 96, Wc = 96;
constexpr int G = 8, OG = 8, IG = 8, KK = 7, PAD = 3;
constexpr int TH = 32, TW = 16;
constexpr int RPT = 4;             // rows (pixels) per thread
constexpr int NT = 128;            // threads per block
constexpr int SH = TH + KK - 1;    // 38 halo rows
constexpr int SWD = TW + KK - 1;   // 22 halo cols (data)
constexpr int SW2 = 25;            // LDS row stride in float2 units
constexpr int TILES_H = Hc / TH, TILES_W = Wc / TW;  // 3 x 6
constexpr int TILES = TILES_H * TILES_W;             // 18
constexpr int PLANE = Hc * Wc;
constexpr int OCB = 2;             // output channels per block (4 quarters)
constexpr int NB = Bc * G * 4 * TILES;               // 2304
constexpr float LOG2E = 1.4426950408889634f;

// Phase-2 tap loops. HALFC literal: 0 -> emb varies with patch row, 1 -> col.
#define PHASE2(HALFC)                                                             \
  _Pragma("unroll 1")                                                             \
  for (int oc = 0; oc < OCB; ++oc) {                                              \
    float qe[RPT][KK];                                                            \
    _Pragma("unroll")                                                             \
    for (int p = 0; p < RPT; ++p)                                                 \
      _Pragma("unroll")                                                           \
      for (int t = 0; t < KK; ++t)                                                \
        qe[p][t] = qv[oc][p] * eb[oc * KK + t];                                   \
    float sa[RPT], sb[RPT], oa[RPT], obv[RPT];                                    \
    _Pragma("unroll")                                                             \
    for (int p = 0; p < RPT; ++p) { sa[p]=0.f; sb[p]=0.f; oa[p]=0.f; obv[p]=0.f; }\
    const float2* rp = &kvs[oc][r0][tx];                                          \
    _Pragma("unroll")                                                             \
    for (int i = 0; i < RPT + KK - 1; ++i) {                                      \
      float2 row[KK];                                                             \
      _Pragma("unroll")                                                           \
      for (int j = 0; j < KK; ++j) row[j] = rp[i * SW2 + j];                      \
      _Pragma("unroll")                                                           \
      for (int p = 0; p < RPT; ++p) {                                             \
        if (i >= p && i - p < KK) {                                               \
          const float qvp = qv[oc][p];                                            \
          _Pragma("unroll")                                                       \
          for (int j = 0; j < KK; ++j) {                                          \
            const float ev = __builtin_amdgcn_exp2f(                              \
                fmaf(qvp, row[j].x, qe[p][(HALFC) ? j : (i - p)]));               \
            if (j & 1) { sb[p] += ev; obv[p] = fmaf(ev, row[j].y, obv[p]); }      \
            else       { sa[p] += ev; oa[p]  = fmaf(ev, row[j].y, oa[p]);  }      \
          }                                                                       \
        }                                                                         \
      }                                                                           \
    }                                                                             \
    _Pragma("unroll")                                                             \
    for (int p = 0; p < RPT; ++p)                                                 \
      ob[oc * PLANE + p * Wc] =                                                   \
          (oa[p] + obv[p]) * __builtin_amdgcn_rcpf(sa[p] + sb[p]);                \
  }

__global__ __launch_bounds__(NT)
void sasa_kernel(const float* __restrict__ x,
                 const float* __restrict__ wq,
                 const float* __restrict__ wk,
                 const float* __restrict__ wv,
                 const float* __restrict__ h_emb,
                 const float* __restrict__ w_emb,
                 float* __restrict__ out)
{
    __shared__ float2 kvs[OCB][SH][SW2];   // 15200 B

    const int tid = threadIdx.x;
    // XCD-aware bijective swizzle: each XCD owns 288 consecutive logical blocks.
    const int L = (blockIdx.x & 7) * (NB / 8) + (blockIdx.x >> 3);
    const int tile    = L % TILES;
    const int rest    = L / TILES;
    const int quarter = rest & 3;      // oc_global = quarter*2 + {0,1}
    const int gi      = (rest >> 2) & 7;
    const int b       = rest >> 5;
    const int half    = quarter >> 1;  // 0 -> h_emb, 1 -> w_emb
    const int th0     = (tile / TILES_W) * TH;
    const int tw0     = (tile % TILES_W) * TW;

    const float* xb  = x  + (size_t)(b * Cc + gi * IG) * PLANE;
    const float* wqg = wq + gi * OG * IG + quarter * OCB * IG;  // block-uniform
    const float* wkg = wk + gi * OG * IG + quarter * OCB * IG;
    const float* wvg = wv + gi * OG * IG + quarter * OCB * IG;
    const float* eb  = (half ? w_emb : h_emb) + gi * (OG / 2) * KK
                                              + (quarter & 1) * OCB * KK;

    // ---- q-pixel loads issued first so HBM latency hides under phase 1 ----
    const int tx = tid & 15;
    const int r0 = RPT * (tid >> 4);   // local rows r0..r0+3
    const int h0 = th0 + r0;
    const int wg = tw0 + tx;
    float xc[RPT][IG];
    {
        const float* xp = xb + (size_t)h0 * Wc + wg;
        #pragma unroll
        for (int p = 0; p < RPT; ++p)
            #pragma unroll
            for (int i = 0; i < IG; ++i)
                xc[p][i] = xp[i * PLANE + p * Wc];
    }

    // ---- Phase 1: k,v (grouped 1x1 conv) over 38x22 halo -> LDS float2 ----
    for (int e = tid; e < SH * SWD; e += NT) {
        const int hy = e / SWD, hx = e - hy * SWD;
        const int gy = th0 + hy - PAD;
        const int gx = tw0 + hx - PAD;
        const bool valid = ((unsigned)gy < (unsigned)Hc) && ((unsigned)gx < (unsigned)Wc);
        float xv[IG];
        #pragma unroll
        for (int i = 0; i < IG; ++i)
            xv[i] = valid ? xb[i * PLANE + gy * Wc + gx] : 0.0f;
        #pragma unroll
        for (int oc = 0; oc < OCB; ++oc) {
            float ka = 0.f, va = 0.f;
            #pragma unroll
            for (int i = 0; i < IG; ++i) {
                ka = fmaf(xv[i], wkg[oc * IG + i], ka);
                va = fmaf(xv[i], wvg[oc * IG + i], va);
            }
            kvs[oc][hy][hx] = make_float2(ka, va);
        }
    }

    // q projections before the barrier; xc registers retire here.
    float qv[OCB][RPT];
    #pragma unroll
    for (int oc = 0; oc < OCB; ++oc)
        #pragma unroll
        for (int p = 0; p < RPT; ++p) {
            float q = 0.f;
            #pragma unroll
            for (int i = 0; i < IG; ++i)
                q = fmaf(xc[p][i], wqg[oc * IG + i], q);
            qv[oc][p] = q * LOG2E;
        }
    __syncthreads();

    // ---- Phase 2: attention; thread owns pixels (r0..r0+3, tx) ----
    float* ob = out + (size_t)(b * Cc + gi * OG + quarter * OCB) * PLANE
                    + (size_t)h0 * Wc + wg;

    if (half == 0) { PHASE2(0) } else { PHASE2(1) }
}

extern "C" void kernel_launch(void* const* d_in, const int* in_sizes, int n_in,
                              void* d_out, int out_size, void* d_ws, size_t ws_size,
                              hipStream_t stream)
{
    const float* x     = (const float*)d_in[0];
    const float* wq    = (const float*)d_in[1];
    const float* wk    = (const float*)d_in[2];
    const float* wv    = (const float*)d_in[3];
    const float* h_emb = (const float*)d_in[4];
    const float* w_emb = (const float*)d_in[5];
    float* out = (float*)d_out;

    sasa_kernel<<<NB, NT, 0, stream>>>(x, wq, wk, wv, h_emb, w_emb, out);
}